// Round 1
// baseline (497.959 us; speedup 1.0000x reference)
//
#include <hip/hip_runtime.h>
#include <math.h>

#define EPS_ 1e-8f
#define LAM_ 1e-3f

// ---------------- K1: 5x5 conv s2 p2 + BN + ReLU ----------------
// x (64,1,32,32) -> y (64,16,16,64) layout (b,h,w,ch)
__global__ __launch_bounds__(256) void k_conv_bn(
    const float* __restrict__ x, const float* __restrict__ cw, const float* __restrict__ cb,
    const float* __restrict__ g, const float* __restrict__ bb,
    const float* __restrict__ mean, const float* __restrict__ var,
    float* __restrict__ y)
{
    int t = blockIdx.x * 256 + threadIdx.x;          // < 64*16*16*64
    int ch = t & 63, w = (t >> 6) & 15, h = (t >> 10) & 15, b = t >> 14;
    const float* xb = x + b * 1024;
    const float* wc = cw + ch * 25;
    float acc = cb[ch];
    #pragma unroll
    for (int kh = 0; kh < 5; ++kh) {
        int ih = h * 2 - 2 + kh;
        if (ih < 0 || ih > 31) continue;
        #pragma unroll
        for (int kw = 0; kw < 5; ++kw) {
            int iw = w * 2 - 2 + kw;
            if (iw < 0 || iw > 31) continue;
            acc = fmaf(xb[ih * 32 + iw], wc[kh * 5 + kw], acc);
        }
    }
    float v = (acc - mean[ch]) * (g[ch] * rsqrtf(var[ch] + 1e-3f)) + bb[ch];
    y[t] = fmaxf(v, 0.f);
}

// ---------------- K2: primary caps (two 1x1 convs) ----------------
// y (b,h,w,64) -> poseP (b,h,w,128), aP (b,h,w,8) [sigmoid]
__global__ __launch_bounds__(256) void k_prim(
    const float* __restrict__ y, const float* __restrict__ pw, const float* __restrict__ pb,
    const float* __restrict__ aw, const float* __restrict__ ab,
    float* __restrict__ poseP, float* __restrict__ aP)
{
    int t = blockIdx.x * 256 + threadIdx.x;
    const int total = 64 * 256 * 136;
    if (t >= total) return;
    int o = t % 136;
    int pos = t / 136;
    const float* yp = y + pos * 64;
    if (o < 128) {
        const float* wp = pw + o * 64;
        float acc = pb[o];
        #pragma unroll
        for (int ch = 0; ch < 64; ++ch) acc = fmaf(yp[ch], wp[ch], acc);
        poseP[pos * 128 + o] = acc;
    } else {
        int oo = o - 128;
        const float* wp = aw + oo * 64;
        float acc = ab[oo];
        #pragma unroll
        for (int ch = 0; ch < 64; ++ch) acc = fmaf(yp[ch], wp[ch], acc);
        aP[pos * 8 + oo] = 1.f / (1.f + expf(-acc));
    }
}

// ---------------- K3/K4: capsule layer with fuzzy routing ----------------
// One block (256 thr) per routing position. v is recomputed in each pass from
// LDS-resident pp and global (L1/L2-cached) W:  v[i,c,e] = sum_q pp[i][p*4+q]*W[i,c][q*4+r]
template<int N, int C, int K, int S, int H, int W, int Bi, int OH, int OW, bool COORDS>
__global__ __launch_bounds__(256) void k_caps(
    const float* __restrict__ pose_in,  // (b,H,W,Bi,16)
    const float* __restrict__ a_in,     // (b,H,W,Bi)
    const float* __restrict__ Wm,       // conv: (N,C,16) ; class: (Bi,C,16)
    const float* __restrict__ bu, const float* __restrict__ ba,
    float* __restrict__ pose_out,       // (b,OH,OW,C,16) (unused for class)
    float* __restrict__ a_out)          // (b,OH,OW,C)
{
    __shared__ float pp[N * 16];
    __shared__ float ap[N];
    __shared__ float coeff0[N];
    __shared__ float mu0[16 * 17];      // stride 17: avoid bank conflicts
    __shared__ float rm1[N * 16];
    __shared__ float red[256];
    __shared__ float rsum_s[16], invden_s[16], s0_s[16];

    const int t = threadIdx.x;
    const int n_ = blockIdx.x;
    const int b = n_ / (OH * OW);
    const int rem = n_ % (OH * OW);
    const int oh = rem / OW, ow = rem % OW;

    // ---- gather patch pose/activation into LDS ----
    for (int idx = t; idx < N * 16; idx += 256) {
        int i = idx >> 4, e = idx & 15;
        int bi = i % Bi;
        int sh, sw;
        if constexpr (COORDS) { int hw = i / Bi; sw = hw % W; sh = hw / W; }
        else { int k2 = i / Bi; sw = ow * S + (k2 % K); sh = oh * S + (k2 / K); }
        pp[idx] = pose_in[(((b * H + sh) * W + sw) * Bi + bi) * 16 + e];
    }
    for (int i = t; i < N; i += 256) {
        int bi = i % Bi;
        int sh, sw;
        if constexpr (COORDS) { int hw = i / Bi; sw = hw % W; sh = hw / W; }
        else { int k2 = i / Bi; sw = ow * S + (k2 % K); sh = oh * S + (k2 / K); }
        ap[i] = a_in[((b * H + sh) * W + sw) * Bi + bi];
    }
    __syncthreads();

    // ---- coeff0[i] = a[i] / (sum a + C^2*EPS)  (t=0 coeff is c-independent) ----
    float part = 0.f;
    for (int i = t; i < N; i += 256) part += ap[i];
    red[t] = part;
    __syncthreads();
    #pragma unroll
    for (int s = 128; s > 0; s >>= 1) { if (t < s) red[t] += red[t + s]; __syncthreads(); }
    float inv0 = 1.f / (red[0] + (float)(C * C) * EPS_);
    for (int i = t; i < N; i += 256) coeff0[i] = ap[i] * inv0;
    __syncthreads();

    const int c = t >> 4, e = t & 15;
    const int p4 = e & 12, r = e & 3;

    // ---- pass A: mu0[c][e] ----
    if (c < C) {
        float mu = 0.f;
        #pragma unroll 4
        for (int i = 0; i < N; ++i) {
            const float* pi = pp + i * 16;
            int widx = COORDS ? (i % Bi) : i;
            const float* wp = Wm + (widx * C + c) * 16;
            float v = pi[p4] * wp[r] + pi[p4 + 1] * wp[4 + r] + pi[p4 + 2] * wp[8 + r] + pi[p4 + 3] * wp[12 + r];
            if constexpr (COORDS) {
                if (e == 0) v += (float)(i / (W * Bi)) * (1.f / H);
                if (e == 1) v += (float)((i / Bi) % W) * (1.f / W);
            }
            mu = fmaf(coeff0[i], v, mu);
        }
        mu0[c * 17 + e] = mu;
    }
    __syncthreads();

    // ---- pass B: dist -> r -> rm1 ----
    {
        const int ig = t >> 4, cc = t & 15;
        for (int i = ig; i < N; i += 16) {
            float inv = 0.f;
            if (cc < C) {
                int widx = COORDS ? (i % Bi) : i;
                float piv[16], wpv[16];
                #pragma unroll
                for (int q = 0; q < 16; ++q) piv[q] = pp[i * 16 + q];
                #pragma unroll
                for (int q = 0; q < 16; ++q) wpv[q] = Wm[(widx * C + cc) * 16 + q];
                float chv = 0.f, cwv = 0.f;
                if constexpr (COORDS) {
                    chv = (float)(i / (W * Bi)) * (1.f / H);
                    cwv = (float)((i / Bi) % W) * (1.f / W);
                }
                float dist = EPS_;
                #pragma unroll
                for (int e2 = 0; e2 < 16; ++e2) {
                    int q4 = e2 & 12, rr = e2 & 3;
                    float v = piv[q4] * wpv[rr] + piv[q4 + 1] * wpv[4 + rr] + piv[q4 + 2] * wpv[8 + rr] + piv[q4 + 3] * wpv[12 + rr];
                    if constexpr (COORDS) { if (e2 == 0) v += chv; if (e2 == 1) v += cwv; }
                    float d = v - mu0[cc * 17 + e2];
                    dist = fmaf(d, d, dist);
                }
                inv = 1.f / dist;
            }
            float s = inv;
            #pragma unroll
            for (int m = 1; m < 16; m <<= 1) s += __shfl_xor(s, m, 64);
            float rmv = 0.f;
            if (cc < C) {
                float r1 = inv / (s + EPS_);
                rmv = r1 * r1 * ap[i];
            }
            rm1[i * 16 + cc] = rmv;
        }
    }
    __syncthreads();

    // ---- r_sum[c] = sum_i rm1 ; invden ; S0 ----
    {
        const int ig = t >> 4, cc = t & 15;
        float partc = 0.f;
        for (int i = ig; i < N; i += 16) partc += rm1[i * 16 + cc];
        red[t] = partc;
        __syncthreads();
        if (t < 16) {
            float s = 0.f;
            #pragma unroll
            for (int k = 0; k < 16; ++k) s += red[k * 16 + t];
            rsum_s[t] = s;
            float id = 1.f / (s + EPS_);
            invden_s[t] = id;
            s0_s[t] = s * id;
        }
        __syncthreads();
    }

    // ---- pass C: mu1, sigma (expanded), cost, a_out ----
    if (c < C) {
        float Sv = 0.f, Sv2 = 0.f;
        const float id = invden_s[c];
        #pragma unroll 4
        for (int i = 0; i < N; ++i) {
            const float* pi = pp + i * 16;
            int widx = COORDS ? (i % Bi) : i;
            const float* wp = Wm + (widx * C + c) * 16;
            float v = pi[p4] * wp[r] + pi[p4 + 1] * wp[4 + r] + pi[p4 + 2] * wp[8 + r] + pi[p4 + 3] * wp[12 + r];
            if constexpr (COORDS) {
                if (e == 0) v += (float)(i / (W * Bi)) * (1.f / H);
                if (e == 1) v += (float)((i / Bi) % W) * (1.f / W);
            }
            float co = rm1[i * 16 + c] * id;
            Sv = fmaf(co, v, Sv);
            Sv2 = fmaf(co * v, v, Sv2);
        }
        // sigma = Sv2 - 2*mu*Sv + mu^2*S0 + EPS  with mu = Sv
        float sigma = fmaxf(Sv2 + Sv * Sv * (s0_s[c] - 2.f), 0.f) + EPS_;
        float cost = (bu[c] + 0.5f * logf(sigma)) * rsum_s[c];
        float cs = cost;
        #pragma unroll
        for (int m = 1; m < 16; m <<= 1) cs += __shfl_xor(cs, m, 64);
        if constexpr (!COORDS) {
            pose_out[(n_ * C + c) * 16 + e] = Sv;
            if (e == 0) a_out[n_ * C + c] = 1.f / (1.f + expf(-(LAM_ * (ba[c] - cs))));
        } else {
            if (e == 0) a_out[b * C + c] = 1.f / (1.f + expf(-(LAM_ * (ba[c] - cs))));
        }
    }
}

extern "C" void kernel_launch(void* const* d_in, const int* in_sizes, int n_in,
                              void* d_out, int out_size, void* d_ws, size_t ws_size,
                              hipStream_t stream)
{
    const float* x   = (const float*)d_in[0];
    const float* c1w = (const float*)d_in[1];
    const float* c1b = (const float*)d_in[2];
    const float* bng = (const float*)d_in[3];
    const float* bnb = (const float*)d_in[4];
    const float* bnm = (const float*)d_in[5];
    const float* bnv = (const float*)d_in[6];
    const float* ppw = (const float*)d_in[7];
    const float* ppb = (const float*)d_in[8];
    const float* paw = (const float*)d_in[9];
    const float* pab = (const float*)d_in[10];
    const float* w1  = (const float*)d_in[11];
    const float* bu1 = (const float*)d_in[12];
    const float* ba1 = (const float*)d_in[13];
    const float* w2  = (const float*)d_in[14];
    const float* bu2 = (const float*)d_in[15];
    const float* ba2 = (const float*)d_in[16];
    const float* wcp = (const float*)d_in[17];
    const float* buc = (const float*)d_in[18];
    const float* bac = (const float*)d_in[19];
    float* out = (float*)d_out;

    float* ws    = (float*)d_ws;
    float* y     = ws;               // 64*16*16*64      = 1048576
    float* poseP = y + 1048576;      // 64*16*16*128     = 2097152
    float* aP    = poseP + 2097152;  // 64*16*16*8       = 131072
    float* pose1 = aP + 131072;      // 64*7*7*16*16     = 802816
    float* a1    = pose1 + 802816;   // 64*7*7*16        = 50176
    float* pose2 = a1 + 50176;       // 64*5*5*16*16     = 409600
    float* a2    = pose2 + 409600;   // 64*5*5*16        = 25600

    hipLaunchKernelGGL(k_conv_bn, dim3(4096), dim3(256), 0, stream,
                       x, c1w, c1b, bng, bnb, bnm, bnv, y);
    hipLaunchKernelGGL(k_prim, dim3((64 * 256 * 136 + 255) / 256), dim3(256), 0, stream,
                       y, ppw, ppb, paw, pab, poseP, aP);
    // stage 1: H=W=16, Bi=8, K=3, S=2 -> 7x7, C=16, N=72
    hipLaunchKernelGGL((k_caps<72, 16, 3, 2, 16, 16, 8, 7, 7, false>), dim3(64 * 7 * 7), dim3(256), 0, stream,
                       poseP, aP, w1, bu1, ba1, pose1, a1);
    // stage 2: H=W=7, Bi=16, K=3, S=1 -> 5x5, C=16, N=144
    hipLaunchKernelGGL((k_caps<144, 16, 3, 1, 7, 7, 16, 5, 5, false>), dim3(64 * 5 * 5), dim3(256), 0, stream,
                       pose1, a1, w2, bu2, ba2, pose2, a2);
    // class: H=W=5, Bi=16, N=400, C=10, coords
    hipLaunchKernelGGL((k_caps<400, 10, 1, 1, 5, 5, 16, 1, 1, true>), dim3(64), dim3(256), 0, stream,
                       pose2, a2, wcp, buc, bac, nullptr, out);
}

// Round 2
// 416.288 us; speedup vs baseline: 1.1962x; 1.1962x over previous
//
#include <hip/hip_runtime.h>
#include <math.h>

#define EPS_ 1e-8f
#define LAM_ 1e-3f

// ---------------- K1: 5x5 conv s2 p2 + BN + ReLU ----------------
__global__ __launch_bounds__(256) void k_conv_bn(
    const float* __restrict__ x, const float* __restrict__ cw, const float* __restrict__ cb,
    const float* __restrict__ g, const float* __restrict__ bb,
    const float* __restrict__ mean, const float* __restrict__ var,
    float* __restrict__ y)
{
    int t = blockIdx.x * 256 + threadIdx.x;          // < 64*16*16*64
    int ch = t & 63, w = (t >> 6) & 15, h = (t >> 10) & 15, b = t >> 14;
    const float* xb = x + b * 1024;
    const float* wc = cw + ch * 25;
    float acc = cb[ch];
    #pragma unroll
    for (int kh = 0; kh < 5; ++kh) {
        int ih = h * 2 - 2 + kh;
        if (ih < 0 || ih > 31) continue;
        #pragma unroll
        for (int kw = 0; kw < 5; ++kw) {
            int iw = w * 2 - 2 + kw;
            if (iw < 0 || iw > 31) continue;
            acc = fmaf(xb[ih * 32 + iw], wc[kh * 5 + kw], acc);
        }
    }
    float v = (acc - mean[ch]) * (g[ch] * rsqrtf(var[ch] + 1e-3f)) + bb[ch];
    y[t] = fmaxf(v, 0.f);
}

// ---------------- K2: primary caps (two 1x1 convs) ----------------
__global__ __launch_bounds__(256) void k_prim(
    const float* __restrict__ y, const float* __restrict__ pw, const float* __restrict__ pb,
    const float* __restrict__ aw, const float* __restrict__ ab,
    float* __restrict__ poseP, float* __restrict__ aP)
{
    int t = blockIdx.x * 256 + threadIdx.x;
    const int total = 64 * 256 * 136;
    if (t >= total) return;
    int o = t % 136;
    int pos = t / 136;
    const float* yp = y + pos * 64;
    if (o < 128) {
        const float* wp = pw + o * 64;
        float acc = pb[o];
        #pragma unroll
        for (int ch = 0; ch < 64; ++ch) acc = fmaf(yp[ch], wp[ch], acc);
        poseP[pos * 128 + o] = acc;
    } else {
        int oo = o - 128;
        const float* wp = aw + oo * 64;
        float acc = ab[oo];
        #pragma unroll
        for (int ch = 0; ch < 64; ++ch) acc = fmaf(yp[ch], wp[ch], acc);
        aP[pos * 8 + oo] = 1.f / (1.f + expf(-acc));
    }
}

// ---------------- K-transpose: W[ic][q*4+r] -> Wt[ic][r*4+q] ----------------
// segments: w1 72*16=1152 mats, w2 144*16=2304 mats, wc 16*10=160 mats
__global__ __launch_bounds__(256) void k_transw(
    const float* __restrict__ w1, const float* __restrict__ w2, const float* __restrict__ wc,
    float* __restrict__ w1t, float* __restrict__ w2t, float* __restrict__ wct)
{
    int t = blockIdx.x * 256 + threadIdx.x;
    if (t >= 3616 * 16) return;
    int m = t >> 4, e = t & 15, r = e >> 2, q = e & 3;
    const float* src; float* dst;
    if (m < 1152)      { src = w1 + m * 16;          dst = w1t + m * 16; }
    else if (m < 3456) { src = w2 + (m - 1152) * 16; dst = w2t + (m - 1152) * 16; }
    else               { src = wc + (m - 3456) * 16; dst = wct + (m - 3456) * 16; }
    dst[e] = src[q * 4 + r];
}

// ---------------- capsule layer with fuzzy routing ----------------
// One block per routing position. Votes recomputed per pass:
// v[i,c,e=p*4+r] = dot4(pp[i][p*4..], Wt[i,c][r*4..])  (Wt is r-major transposed)
// BLK=256: thread=(c,e). BLK=1024 (class): 4-way i-split, partials reduced in LDS.
template<int N, int C, int K, int S, int H, int W, int Bi, int OH, int OW, bool COORDS, int BLK>
__global__ __launch_bounds__(BLK) void k_caps(
    const float* __restrict__ pose_in,  // (b,H,W,Bi,16)
    const float* __restrict__ a_in,     // (b,H,W,Bi)
    const float* __restrict__ Wt,       // transposed weights
    const float* __restrict__ bu, const float* __restrict__ ba,
    float* __restrict__ pose_out,       // (b,OH,OW,C,16)
    float* __restrict__ a_out)          // (b,OH,OW,C)
{
    constexpr int ZS = BLK / 256;
    constexpr int CHUNK = (N + ZS - 1) / ZS;
    __shared__ __align__(16) float pp[N * 16];
    __shared__ float ap[N];
    __shared__ float coeff0[N];
    __shared__ float mu0[16 * 17];
    __shared__ float rm1[N * 16];
    __shared__ float red[BLK];
    __shared__ float red2[BLK];
    __shared__ float rsum_s[16], invden_s[16], s0_s[16];

    const int t = threadIdx.x;
    const int n_ = blockIdx.x;
    const int b = n_ / (OH * OW);
    const int rem = n_ % (OH * OW);
    const int oh = rem / OW, ow = rem % OW;

    // ---- gather patch pose (float4) and activation into LDS ----
    for (int idx = t; idx < N * 4; idx += BLK) {
        int i = idx >> 2, f = idx & 3;
        int bi = i % Bi;
        int sh, sw;
        if constexpr (COORDS) { int hw = i / Bi; sw = hw % W; sh = hw / W; }
        else { int k2 = i / Bi; sw = ow * S + (k2 % K); sh = oh * S + (k2 / K); }
        const float4* src = (const float4*)(pose_in + (((b * H + sh) * W + sw) * Bi + bi) * 16);
        ((float4*)(pp + i * 16))[f] = src[f];
    }
    for (int i = t; i < N; i += BLK) {
        int bi = i % Bi;
        int sh, sw;
        if constexpr (COORDS) { int hw = i / Bi; sw = hw % W; sh = hw / W; }
        else { int k2 = i / Bi; sw = ow * S + (k2 % K); sh = oh * S + (k2 / K); }
        ap[i] = a_in[((b * H + sh) * W + sw) * Bi + bi];
    }
    __syncthreads();

    // ---- coeff0[i] = a[i] / (sum a + C^2*EPS) ----
    float part = 0.f;
    for (int i = t; i < N; i += BLK) part += ap[i];
    red[t] = part;
    __syncthreads();
    #pragma unroll
    for (int s = BLK / 2; s > 0; s >>= 1) { if (t < s) red[t] += red[t + s]; __syncthreads(); }
    float inv0 = 1.f / (red[0] + (float)(C * C) * EPS_);
    for (int i = t; i < N; i += BLK) coeff0[i] = ap[i] * inv0;
    __syncthreads();

    const int z = t >> 8;           // 0 for BLK=256
    const int tt = t & 255;
    const int c = tt >> 4, e = tt & 15;
    const int p4 = e & 12, r4 = (e & 3) * 4;
    const int i0 = z * CHUNK;
    const int i1 = (i0 + CHUNK < N) ? (i0 + CHUNK) : N;

    // ---- pass A: mu0 ----
    float muA = 0.f;
    if (c < C) {
        #pragma unroll 4
        for (int i = i0; i < i1; ++i) {
            int widx = COORDS ? (i % Bi) : i;
            float4 pv = *(const float4*)(pp + i * 16 + p4);
            float4 wv = *(const float4*)(Wt + (widx * C + c) * 16 + r4);
            float v = pv.x * wv.x + pv.y * wv.y + pv.z * wv.z + pv.w * wv.w;
            if constexpr (COORDS) {
                if (e == 0) v += (float)(i / (W * Bi)) * (1.f / H);
                if (e == 1) v += (float)((i / Bi) % W) * (1.f / W);
            }
            muA = fmaf(coeff0[i], v, muA);
        }
    }
    if constexpr (ZS == 1) {
        if (c < C) mu0[c * 17 + e] = muA;
    } else {
        red[z * 256 + tt] = muA;
        __syncthreads();
        if (z == 0 && c < C) {
            float m = muA;
            #pragma unroll
            for (int zz = 1; zz < ZS; ++zz) m += red[zz * 256 + tt];
            mu0[c * 17 + e] = m;
        }
    }
    __syncthreads();

    // ---- pass B: dist -> r -> rm1 ----
    {
        const int ig = t >> 4, cc = t & 15;
        for (int i = ig; i < N; i += BLK / 16) {
            float inv = 0.f;
            if (cc < C) {
                int widx = COORDS ? (i % Bi) : i;
                const float4* pi4 = (const float4*)(pp + i * 16);
                const float4* wt4 = (const float4*)(Wt + (widx * C + cc) * 16);
                float4 pv0 = pi4[0], pv1 = pi4[1], pv2 = pi4[2], pv3 = pi4[3];
                float4 wv0 = wt4[0], wv1 = wt4[1], wv2 = wt4[2], wv3 = wt4[3];
                float chv = 0.f, cwv = 0.f;
                if constexpr (COORDS) {
                    chv = (float)(i / (W * Bi)) * (1.f / H);
                    cwv = (float)((i / Bi) % W) * (1.f / W);
                }
                float dist = EPS_;
                #pragma unroll
                for (int e2 = 0; e2 < 16; ++e2) {
                    float4 pv = (e2 < 4) ? pv0 : (e2 < 8) ? pv1 : (e2 < 12) ? pv2 : pv3;
                    float4 wv = ((e2 & 3) == 0) ? wv0 : ((e2 & 3) == 1) ? wv1 : ((e2 & 3) == 2) ? wv2 : wv3;
                    float v = pv.x * wv.x + pv.y * wv.y + pv.z * wv.z + pv.w * wv.w;
                    if constexpr (COORDS) { if (e2 == 0) v += chv; if (e2 == 1) v += cwv; }
                    float d = v - mu0[cc * 17 + e2];
                    dist = fmaf(d, d, dist);
                }
                inv = 1.f / dist;
            }
            float s = inv;
            #pragma unroll
            for (int m = 1; m < 16; m <<= 1) s += __shfl_xor(s, m, 64);
            float rmv = 0.f;
            if (cc < C) {
                float r1 = inv / (s + EPS_);
                rmv = r1 * r1 * ap[i];
            }
            rm1[i * 16 + cc] = rmv;
        }
    }
    __syncthreads();

    // ---- r_sum[c], invden, S0 ----
    {
        const int ig = t >> 4, cc = t & 15;
        float partc = 0.f;
        for (int i = ig; i < N; i += BLK / 16) partc += rm1[i * 16 + cc];
        red[t] = partc;
        __syncthreads();
        if (t < 16) {
            float s = 0.f;
            #pragma unroll
            for (int k = 0; k < BLK / 16; ++k) s += red[k * 16 + t];
            rsum_s[t] = s;
            float id = 1.f / (s + EPS_);
            invden_s[t] = id;
            s0_s[t] = s * id;
        }
        __syncthreads();
    }

    // ---- pass C: mu1 (=Sv), sigma expanded, cost, outputs ----
    float Sv = 0.f, Sv2 = 0.f;
    if (c < C) {
        const float id = invden_s[c];
        #pragma unroll 4
        for (int i = i0; i < i1; ++i) {
            int widx = COORDS ? (i % Bi) : i;
            float4 pv = *(const float4*)(pp + i * 16 + p4);
            float4 wv = *(const float4*)(Wt + (widx * C + c) * 16 + r4);
            float v = pv.x * wv.x + pv.y * wv.y + pv.z * wv.z + pv.w * wv.w;
            if constexpr (COORDS) {
                if (e == 0) v += (float)(i / (W * Bi)) * (1.f / H);
                if (e == 1) v += (float)((i / Bi) % W) * (1.f / W);
            }
            float co = rm1[i * 16 + c] * id;
            Sv = fmaf(co, v, Sv);
            Sv2 = fmaf(co * v, v, Sv2);
        }
    }
    if constexpr (ZS > 1) {
        red[z * 256 + tt] = Sv;
        red2[z * 256 + tt] = Sv2;
        __syncthreads();
        if (z == 0 && c < C) {
            #pragma unroll
            for (int zz = 1; zz < ZS; ++zz) { Sv += red[zz * 256 + tt]; Sv2 += red2[zz * 256 + tt]; }
        }
    }
    if ((ZS == 1 || z == 0) && c < C) {
        // sigma = Sv2 - 2*mu*Sv + mu^2*S0 + EPS  with mu = Sv
        float sigma = fmaxf(Sv2 + Sv * Sv * (s0_s[c] - 2.f), 0.f) + EPS_;
        float cost = (bu[c] + 0.5f * logf(sigma)) * rsum_s[c];
        float cs = cost;
        #pragma unroll
        for (int m = 1; m < 16; m <<= 1) cs += __shfl_xor(cs, m, 64);  // sum over e
        if constexpr (!COORDS) {
            pose_out[(n_ * C + c) * 16 + e] = Sv;
            if (e == 0) a_out[n_ * C + c] = 1.f / (1.f + expf(-(LAM_ * (ba[c] - cs))));
        } else {
            if (e == 0) a_out[b * C + c] = 1.f / (1.f + expf(-(LAM_ * (ba[c] - cs))));
        }
    }
}

extern "C" void kernel_launch(void* const* d_in, const int* in_sizes, int n_in,
                              void* d_out, int out_size, void* d_ws, size_t ws_size,
                              hipStream_t stream)
{
    const float* x   = (const float*)d_in[0];
    const float* c1w = (const float*)d_in[1];
    const float* c1b = (const float*)d_in[2];
    const float* bng = (const float*)d_in[3];
    const float* bnb = (const float*)d_in[4];
    const float* bnm = (const float*)d_in[5];
    const float* bnv = (const float*)d_in[6];
    const float* ppw = (const float*)d_in[7];
    const float* ppb = (const float*)d_in[8];
    const float* paw = (const float*)d_in[9];
    const float* pab = (const float*)d_in[10];
    const float* w1  = (const float*)d_in[11];
    const float* bu1 = (const float*)d_in[12];
    const float* ba1 = (const float*)d_in[13];
    const float* w2  = (const float*)d_in[14];
    const float* bu2 = (const float*)d_in[15];
    const float* ba2 = (const float*)d_in[16];
    const float* wcp = (const float*)d_in[17];
    const float* buc = (const float*)d_in[18];
    const float* bac = (const float*)d_in[19];
    float* out = (float*)d_out;

    float* ws    = (float*)d_ws;
    float* y     = ws;               // 64*16*16*64      = 1048576
    float* poseP = y + 1048576;      // 64*16*16*128     = 2097152
    float* aP    = poseP + 2097152;  // 64*16*16*8       = 131072
    float* pose1 = aP + 131072;      // 64*7*7*16*16     = 802816
    float* a1    = pose1 + 802816;   // 64*7*7*16        = 50176
    float* pose2 = a1 + 50176;       // 64*5*5*16*16     = 409600
    float* a2    = pose2 + 409600;   // 64*5*5*16        = 25600
    // transposed weights reuse the y region (y is dead after k_prim):
    float* w1t = y;                  // 72*16*16  = 18432
    float* w2t = y + 18432;          // 144*16*16 = 36864
    float* wct = y + 55296;          // 16*10*16  = 2560   (total 57856 < 1048576)

    hipLaunchKernelGGL(k_conv_bn, dim3(4096), dim3(256), 0, stream,
                       x, c1w, c1b, bng, bnb, bnm, bnv, y);
    hipLaunchKernelGGL(k_prim, dim3((64 * 256 * 136 + 255) / 256), dim3(256), 0, stream,
                       y, ppw, ppb, paw, pab, poseP, aP);
    hipLaunchKernelGGL(k_transw, dim3((3616 * 16 + 255) / 256), dim3(256), 0, stream,
                       w1, w2, wcp, w1t, w2t, wct);
    // stage 1: H=W=16, Bi=8, K=3, S=2 -> 7x7, C=16, N=72
    hipLaunchKernelGGL((k_caps<72, 16, 3, 2, 16, 16, 8, 7, 7, false, 256>), dim3(64 * 7 * 7), dim3(256), 0, stream,
                       poseP, aP, w1t, bu1, ba1, pose1, a1);
    // stage 2: H=W=7, Bi=16, K=3, S=1 -> 5x5, C=16, N=144
    hipLaunchKernelGGL((k_caps<144, 16, 3, 1, 7, 7, 16, 5, 5, false, 256>), dim3(64 * 5 * 5), dim3(256), 0, stream,
                       pose1, a1, w2t, bu2, ba2, pose2, a2);
    // class: H=W=5, Bi=16, N=400, C=10, coords, BLK=1024 (4-way i-split)
    hipLaunchKernelGGL((k_caps<400, 10, 1, 1, 5, 5, 16, 1, 1, true, 1024>), dim3(64), dim3(1024), 0, stream,
                       pose2, a2, wct, buc, bac, nullptr, out);
}

// Round 3
// 349.384 us; speedup vs baseline: 1.4252x; 1.1915x over previous
//
#include <hip/hip_runtime.h>
#include <math.h>

#define EPS_ 1e-8f
#define LAM_ 1e-3f

// ---------------- K1: 5x5 conv s2 p2 + BN + ReLU ----------------
__global__ __launch_bounds__(256) void k_conv_bn(
    const float* __restrict__ x, const float* __restrict__ cw, const float* __restrict__ cb,
    const float* __restrict__ g, const float* __restrict__ bb,
    const float* __restrict__ mean, const float* __restrict__ var,
    float* __restrict__ y)
{
    int t = blockIdx.x * 256 + threadIdx.x;          // < 64*16*16*64
    int ch = t & 63, w = (t >> 6) & 15, h = (t >> 10) & 15, b = t >> 14;
    const float* xb = x + b * 1024;
    const float* wc = cw + ch * 25;
    float acc = cb[ch];
    #pragma unroll
    for (int kh = 0; kh < 5; ++kh) {
        int ih = h * 2 - 2 + kh;
        if (ih < 0 || ih > 31) continue;
        #pragma unroll
        for (int kw = 0; kw < 5; ++kw) {
            int iw = w * 2 - 2 + kw;
            if (iw < 0 || iw > 31) continue;
            acc = fmaf(xb[ih * 32 + iw], wc[kh * 5 + kw], acc);
        }
    }
    float v = (acc - mean[ch]) * (g[ch] * rsqrtf(var[ch] + 1e-3f)) + bb[ch];
    y[t] = fmaxf(v, 0.f);
}

// ---------------- K2: primary caps (two 1x1 convs, float4) ----------------
__global__ __launch_bounds__(256) void k_prim(
    const float* __restrict__ y, const float* __restrict__ pw, const float* __restrict__ pb,
    const float* __restrict__ aw, const float* __restrict__ ab,
    float* __restrict__ poseP, float* __restrict__ aP)
{
    int t = blockIdx.x * 256 + threadIdx.x;
    const int total = 64 * 256 * 136;
    if (t >= total) return;
    int o = t % 136;
    int pos = t / 136;
    const float4* yp = (const float4*)(y + pos * 64);
    if (o < 128) {
        const float4* wp = (const float4*)(pw + o * 64);
        float acc = pb[o];
        #pragma unroll
        for (int j = 0; j < 16; ++j) {
            float4 a4 = yp[j], b4 = wp[j];
            acc += a4.x * b4.x + a4.y * b4.y + a4.z * b4.z + a4.w * b4.w;
        }
        poseP[pos * 128 + o] = acc;
    } else {
        int oo = o - 128;
        const float4* wp = (const float4*)(aw + oo * 64);
        float acc = ab[oo];
        #pragma unroll
        for (int j = 0; j < 16; ++j) {
            float4 a4 = yp[j], b4 = wp[j];
            acc += a4.x * b4.x + a4.y * b4.y + a4.z * b4.z + a4.w * b4.w;
        }
        aP[pos * 8 + oo] = 1.f / (1.f + expf(-acc));
    }
}

// ---------------- K-transpose: W[ic][q*4+r] -> Wt[ic][r*4+q] ----------------
__global__ __launch_bounds__(256) void k_transw(
    const float* __restrict__ w1, const float* __restrict__ w2, const float* __restrict__ wc,
    float* __restrict__ w1t, float* __restrict__ w2t, float* __restrict__ wct)
{
    int t = blockIdx.x * 256 + threadIdx.x;
    if (t >= 3616 * 16) return;
    int m = t >> 4, e = t & 15, r = e >> 2, q = e & 3;
    const float* src; float* dst;
    if (m < 1152)      { src = w1 + m * 16;          dst = w1t + m * 16; }
    else if (m < 3456) { src = w2 + (m - 1152) * 16; dst = w2t + (m - 1152) * 16; }
    else               { src = wc + (m - 3456) * 16; dst = wct + (m - 3456) * 16; }
    dst[e] = src[q * 4 + r];
}

// ---------------- capsule layer with fuzzy routing (2-pass fused) ----------------
// Thread mapping both passes: (ig = t>>4, cc = t&15). Each thread processes
// i in {ig, ig+NIG, ...}, computing all 16 vote components per i in registers.
// Pass A: mu0.  Pass B: dist->rm fused with un-normalized Sv/Sv2/rsum accumulation.
template<int N, int C, int K, int S, int H, int W, int Bi, int OH, int OW, bool COORDS, int BLK>
__global__ __launch_bounds__(BLK) void k_caps(
    const float* __restrict__ pose_in,  // (b,H,W,Bi,16)
    const float* __restrict__ a_in,     // (b,H,W,Bi)
    const float* __restrict__ Wt,       // transposed weights (r-major)
    const float* __restrict__ bu, const float* __restrict__ ba,
    float* __restrict__ pose_out,       // (b,OH,OW,C,16)
    float* __restrict__ a_out)          // (b,OH,OW,C)
{
    constexpr int NW  = BLK / 64;                 // waves per block
    constexpr int NIG = BLK / 16;                 // # i-groups
    constexpr int NIT = (N + NIG - 1) / NIG;      // i iterations per thread

    __shared__ __align__(16) float pp[N * 16];
    __shared__ float ap[N];
    __shared__ float coeff0[N];
    __shared__ float mu0[16 * 17];
    __shared__ float red1[NW * C * 17];
    __shared__ float red2[NW * C * 17];
    __shared__ float redr[NW * C];

    const int t = threadIdx.x;
    const int lane = t & 63;
    const int w = t >> 6;
    const int n_ = blockIdx.x;
    const int b = n_ / (OH * OW);
    const int rem = n_ % (OH * OW);
    const int oh = rem / OW, ow = rem % OW;

    // ---- gather patch pose (float4) and activation into LDS ----
    for (int idx = t; idx < N * 4; idx += BLK) {
        int i = idx >> 2, f = idx & 3;
        int bi = i % Bi;
        int sh, sw;
        if constexpr (COORDS) { int hw = i / Bi; sw = hw % W; sh = hw / W; }
        else { int k2 = i / Bi; sw = ow * S + (k2 % K); sh = oh * S + (k2 / K); }
        const float4* src = (const float4*)(pose_in + (((b * H + sh) * W + sw) * Bi + bi) * 16);
        ((float4*)(pp + i * 16))[f] = src[f];
    }
    for (int i = t; i < N; i += BLK) {
        int bi = i % Bi;
        int sh, sw;
        if constexpr (COORDS) { int hw = i / Bi; sw = hw % W; sh = hw / W; }
        else { int k2 = i / Bi; sw = ow * S + (k2 % K); sh = oh * S + (k2 / K); }
        ap[i] = a_in[((b * H + sh) * W + sw) * Bi + bi];
    }
    __syncthreads();

    // ---- coeff0[i] = a[i] / (sum a + C^2*EPS) ----
    {
        float part = 0.f;
        for (int i = t; i < N; i += BLK) part += ap[i];
        #pragma unroll
        for (int m = 1; m < 64; m <<= 1) part += __shfl_xor(part, m, 64);
        if (lane == 0) red1[w] = part;
        __syncthreads();
        float s = 0.f;
        #pragma unroll
        for (int ww = 0; ww < NW; ++ww) s += red1[ww];
        float inv0 = 1.f / (s + (float)(C * C) * EPS_);
        for (int i = t; i < N; i += BLK) coeff0[i] = ap[i] * inv0;
        __syncthreads();
    }

    const int ig = t >> 4, cc = t & 15;

    // ================= pass A: mu0 =================
    {
        float muU[16];
        #pragma unroll
        for (int e2 = 0; e2 < 16; ++e2) muU[e2] = 0.f;
        if (cc < C) {
            for (int ii = 0; ii < NIT; ++ii) {
                int i = ig + ii * NIG;
                if (i < N) {
                    const float4* pi4 = (const float4*)(pp + i * 16);
                    int widx = COORDS ? (i % Bi) : i;
                    const float4* wt4 = (const float4*)(Wt + (widx * C + cc) * 16);
                    float4 pv[4] = { pi4[0], pi4[1], pi4[2], pi4[3] };
                    float4 wv[4] = { wt4[0], wt4[1], wt4[2], wt4[3] };
                    float co = coeff0[i];
                    float chv = 0.f, cwv = 0.f;
                    if constexpr (COORDS) {
                        chv = (float)(i / (W * Bi)) * (1.f / H);
                        cwv = (float)((i / Bi) % W) * (1.f / W);
                    }
                    #pragma unroll
                    for (int e2 = 0; e2 < 16; ++e2) {
                        float4 p4 = pv[e2 >> 2], w4 = wv[e2 & 3];
                        float v = p4.x * w4.x + p4.y * w4.y + p4.z * w4.z + p4.w * w4.w;
                        if constexpr (COORDS) { if (e2 == 0) v += chv; if (e2 == 1) v += cwv; }
                        muU[e2] = fmaf(co, v, muU[e2]);
                    }
                }
            }
        }
        // wave-level reduce over the 4 in-wave ig groups, then LDS staging
        #pragma unroll
        for (int e2 = 0; e2 < 16; ++e2) {
            float xv = muU[e2];
            xv += __shfl_xor(xv, 16, 64);
            xv += __shfl_xor(xv, 32, 64);
            if (lane < 16 && lane < C) red1[(w * C + lane) * 17 + e2] = xv;
        }
        __syncthreads();
        if (t < 256) {
            int c = t >> 4, e = t & 15;
            if (c < C) {
                float m = 0.f;
                #pragma unroll
                for (int ww = 0; ww < NW; ++ww) m += red1[(ww * C + c) * 17 + e];
                mu0[c * 17 + e] = m;
            }
        }
        __syncthreads();
    }

    // ================= pass B: dist -> rm fused with Sv/Sv2/rsum =================
    {
        float m0[16];
        if (cc < C) {
            #pragma unroll
            for (int e2 = 0; e2 < 16; ++e2) m0[e2] = mu0[cc * 17 + e2];
        }
        float SvU[16], Sv2U[16];
        #pragma unroll
        for (int e2 = 0; e2 < 16; ++e2) { SvU[e2] = 0.f; Sv2U[e2] = 0.f; }
        float rsumP = 0.f;

        for (int ii = 0; ii < NIT; ++ii) {
            int i = ig + ii * NIG;
            bool act = (i < N);
            float inv = 0.f;
            float vv[16];
            if (act && cc < C) {
                const float4* pi4 = (const float4*)(pp + i * 16);
                int widx = COORDS ? (i % Bi) : i;
                const float4* wt4 = (const float4*)(Wt + (widx * C + cc) * 16);
                float4 pv[4] = { pi4[0], pi4[1], pi4[2], pi4[3] };
                float4 wv[4] = { wt4[0], wt4[1], wt4[2], wt4[3] };
                float chv = 0.f, cwv = 0.f;
                if constexpr (COORDS) {
                    chv = (float)(i / (W * Bi)) * (1.f / H);
                    cwv = (float)((i / Bi) % W) * (1.f / W);
                }
                float dist = EPS_;
                #pragma unroll
                for (int e2 = 0; e2 < 16; ++e2) {
                    float4 p4 = pv[e2 >> 2], w4 = wv[e2 & 3];
                    float v = p4.x * w4.x + p4.y * w4.y + p4.z * w4.z + p4.w * w4.w;
                    if constexpr (COORDS) { if (e2 == 0) v += chv; if (e2 == 1) v += cwv; }
                    vv[e2] = v;
                    float d = v - m0[e2];
                    dist = fmaf(d, d, dist);
                }
                inv = 1.f / dist;
            }
            // sum of inv over the 16 capsules c (lanes sharing ig)
            float s = inv;
            #pragma unroll
            for (int m = 1; m < 16; m <<= 1) s += __shfl_xor(s, m, 64);
            if (act && cc < C) {
                float r1 = inv / (s + EPS_);
                float rm = r1 * r1 * ap[i];
                rsumP += rm;
                #pragma unroll
                for (int e2 = 0; e2 < 16; ++e2) {
                    SvU[e2] = fmaf(rm, vv[e2], SvU[e2]);
                    Sv2U[e2] = fmaf(rm * vv[e2], vv[e2], Sv2U[e2]);
                }
            }
        }
        // reduce SvU/Sv2U/rsum across waves
        #pragma unroll
        for (int e2 = 0; e2 < 16; ++e2) {
            float xv = SvU[e2];
            xv += __shfl_xor(xv, 16, 64);
            xv += __shfl_xor(xv, 32, 64);
            float yv = Sv2U[e2];
            yv += __shfl_xor(yv, 16, 64);
            yv += __shfl_xor(yv, 32, 64);
            if (lane < 16 && lane < C) {
                red1[(w * C + lane) * 17 + e2] = xv;
                red2[(w * C + lane) * 17 + e2] = yv;
            }
        }
        {
            float rv = rsumP;
            rv += __shfl_xor(rv, 16, 64);
            rv += __shfl_xor(rv, 32, 64);
            if (lane < 16 && lane < C) redr[w * C + lane] = rv;
        }
        __syncthreads();
    }

    // ================= epilogue =================
    if (t < 256) {
        int c = t >> 4, e = t & 15;
        if (c < C) {
            float SvT = 0.f, Sv2T = 0.f, R = 0.f;
            #pragma unroll
            for (int ww = 0; ww < NW; ++ww) {
                SvT  += red1[(ww * C + c) * 17 + e];
                Sv2T += red2[(ww * C + c) * 17 + e];
                R    += redr[ww * C + c];
            }
            float id = 1.f / (R + EPS_);
            float S0 = R * id;
            float Sv = SvT * id;           // mu1
            float Sv2 = Sv2T * id;
            float sigma = fmaxf(Sv2 + Sv * Sv * (S0 - 2.f), 0.f) + EPS_;
            float cost = (bu[c] + 0.5f * logf(sigma)) * R;
            float cs = cost;
            #pragma unroll
            for (int m = 1; m < 16; m <<= 1) cs += __shfl_xor(cs, m, 64);  // sum over e
            if constexpr (!COORDS) {
                pose_out[(n_ * C + c) * 16 + e] = Sv;
                if (e == 0) a_out[n_ * C + c] = 1.f / (1.f + expf(-(LAM_ * (ba[c] - cs))));
            } else {
                if (e == 0) a_out[b * C + c] = 1.f / (1.f + expf(-(LAM_ * (ba[c] - cs))));
            }
        }
    }
}

extern "C" void kernel_launch(void* const* d_in, const int* in_sizes, int n_in,
                              void* d_out, int out_size, void* d_ws, size_t ws_size,
                              hipStream_t stream)
{
    const float* x   = (const float*)d_in[0];
    const float* c1w = (const float*)d_in[1];
    const float* c1b = (const float*)d_in[2];
    const float* bng = (const float*)d_in[3];
    const float* bnb = (const float*)d_in[4];
    const float* bnm = (const float*)d_in[5];
    const float* bnv = (const float*)d_in[6];
    const float* ppw = (const float*)d_in[7];
    const float* ppb = (const float*)d_in[8];
    const float* paw = (const float*)d_in[9];
    const float* pab = (const float*)d_in[10];
    const float* w1  = (const float*)d_in[11];
    const float* bu1 = (const float*)d_in[12];
    const float* ba1 = (const float*)d_in[13];
    const float* w2  = (const float*)d_in[14];
    const float* bu2 = (const float*)d_in[15];
    const float* ba2 = (const float*)d_in[16];
    const float* wcp = (const float*)d_in[17];
    const float* buc = (const float*)d_in[18];
    const float* bac = (const float*)d_in[19];
    float* out = (float*)d_out;

    float* ws    = (float*)d_ws;
    float* y     = ws;               // 64*16*16*64      = 1048576
    float* poseP = y + 1048576;      // 64*16*16*128     = 2097152
    float* aP    = poseP + 2097152;  // 64*16*16*8       = 131072
    float* pose1 = aP + 131072;      // 64*7*7*16*16     = 802816
    float* a1    = pose1 + 802816;   // 64*7*7*16        = 50176
    float* pose2 = a1 + 50176;       // 64*5*5*16*16     = 409600
    float* a2    = pose2 + 409600;   // 64*5*5*16        = 25600
    // transposed weights reuse the y region (y is dead after k_prim):
    float* w1t = y;                  // 72*16*16  = 18432
    float* w2t = y + 18432;          // 144*16*16 = 36864
    float* wct = y + 55296;          // 16*10*16  = 2560

    hipLaunchKernelGGL(k_conv_bn, dim3(4096), dim3(256), 0, stream,
                       x, c1w, c1b, bng, bnb, bnm, bnv, y);
    hipLaunchKernelGGL(k_prim, dim3((64 * 256 * 136 + 255) / 256), dim3(256), 0, stream,
                       y, ppw, ppb, paw, pab, poseP, aP);
    hipLaunchKernelGGL(k_transw, dim3((3616 * 16 + 255) / 256), dim3(256), 0, stream,
                       w1, w2, wcp, w1t, w2t, wct);
    // stage 1: N=72, C=16
    hipLaunchKernelGGL((k_caps<72, 16, 3, 2, 16, 16, 8, 7, 7, false, 256>), dim3(64 * 7 * 7), dim3(256), 0, stream,
                       poseP, aP, w1t, bu1, ba1, pose1, a1);
    // stage 2: N=144, C=16
    hipLaunchKernelGGL((k_caps<144, 16, 3, 1, 7, 7, 16, 5, 5, false, 256>), dim3(64 * 5 * 5), dim3(256), 0, stream,
                       pose1, a1, w2t, bu2, ba2, pose2, a2);
    // class: N=400, C=10, coords, BLK=1024
    hipLaunchKernelGGL((k_caps<400, 10, 1, 1, 5, 5, 16, 1, 1, true, 1024>), dim3(64), dim3(1024), 0, stream,
                       pose2, a2, wct, buc, bac, nullptr, out);
}

// Round 4
// 280.929 us; speedup vs baseline: 1.7725x; 1.2437x over previous
//
#include <hip/hip_runtime.h>
#include <math.h>

#define EPS_ 1e-8f
#define LAM_ 1e-3f

// ---------------- K1: 5x5 conv s2 p2 + BN + ReLU ----------------
__global__ __launch_bounds__(256) void k_conv_bn(
    const float* __restrict__ x, const float* __restrict__ cw, const float* __restrict__ cb,
    const float* __restrict__ g, const float* __restrict__ bb,
    const float* __restrict__ mean, const float* __restrict__ var,
    float* __restrict__ y)
{
    int t = blockIdx.x * 256 + threadIdx.x;          // < 64*16*16*64
    int ch = t & 63, w = (t >> 6) & 15, h = (t >> 10) & 15, b = t >> 14;
    const float* xb = x + b * 1024;
    const float* wc = cw + ch * 25;
    float acc = cb[ch];
    #pragma unroll
    for (int kh = 0; kh < 5; ++kh) {
        int ih = h * 2 - 2 + kh;
        if (ih < 0 || ih > 31) continue;
        #pragma unroll
        for (int kw = 0; kw < 5; ++kw) {
            int iw = w * 2 - 2 + kw;
            if (iw < 0 || iw > 31) continue;
            acc = fmaf(xb[ih * 32 + iw], wc[kh * 5 + kw], acc);
        }
    }
    float v = (acc - mean[ch]) * (g[ch] * rsqrtf(var[ch] + 1e-3f)) + bb[ch];
    y[t] = fmaxf(v, 0.f);
}

// ---------------- K-prep: all weight transposes ----------------
// part 1: caps W[ic][q*4+r] -> Wt[ic][r*4+q]   (w1:1152, w2:2304, wc:160 mats)
// part 2: prim weights -> wPrimT[j][o], j in [0,65), o in [0,136); row 64 = bias
__global__ __launch_bounds__(256) void k_transw(
    const float* __restrict__ w1, const float* __restrict__ w2, const float* __restrict__ wc,
    const float* __restrict__ pw, const float* __restrict__ pb,
    const float* __restrict__ aw, const float* __restrict__ ab,
    float* __restrict__ w1t, float* __restrict__ w2t, float* __restrict__ wct,
    float* __restrict__ wpt)
{
    int t = blockIdx.x * 256 + threadIdx.x;
    if (t < 3616 * 16) {
        int m = t >> 4, e = t & 15, r = e >> 2, q = e & 3;
        const float* src; float* dst;
        if (m < 1152)      { src = w1 + m * 16;          dst = w1t + m * 16; }
        else if (m < 3456) { src = w2 + (m - 1152) * 16; dst = w2t + (m - 1152) * 16; }
        else               { src = wc + (m - 3456) * 16; dst = wct + (m - 3456) * 16; }
        dst[e] = src[q * 4 + r];
    } else if (t < 3616 * 16 + 65 * 136) {
        int idx = t - 3616 * 16;
        int o = idx % 136, j = idx / 136;
        float v;
        if (j == 64)       v = (o < 128) ? pb[o] : ab[o - 128];
        else if (o < 128)  v = pw[o * 64 + j];
        else               v = aw[(o - 128) * 64 + j];
        wpt[j * 136 + o] = v;
    }
}

// ---------------- K2: primary caps (two 1x1 convs as coalesced GEMM) ----------------
// thread = (pos, oq), oq in [0,34): output quad. wPrimT[j][o] is L1-resident (35 KB).
__global__ __launch_bounds__(256) void k_prim(
    const float* __restrict__ y, const float* __restrict__ wpt,
    float* __restrict__ poseP, float* __restrict__ aP)
{
    int t = blockIdx.x * 256 + threadIdx.x;
    if (t >= 16384 * 34) return;
    int oq = t % 34;
    int pos = t / 34;
    const float* yp = y + pos * 64;
    float4 acc = *(const float4*)(wpt + 64 * 136 + oq * 4);   // bias row
    #pragma unroll
    for (int j0 = 0; j0 < 64; j0 += 4) {
        float4 y4 = *(const float4*)(yp + j0);
        float4 w0 = *(const float4*)(wpt + (j0 + 0) * 136 + oq * 4);
        float4 w1 = *(const float4*)(wpt + (j0 + 1) * 136 + oq * 4);
        float4 w2 = *(const float4*)(wpt + (j0 + 2) * 136 + oq * 4);
        float4 w3 = *(const float4*)(wpt + (j0 + 3) * 136 + oq * 4);
        acc.x = fmaf(y4.x, w0.x, fmaf(y4.y, w1.x, fmaf(y4.z, w2.x, fmaf(y4.w, w3.x, acc.x))));
        acc.y = fmaf(y4.x, w0.y, fmaf(y4.y, w1.y, fmaf(y4.z, w2.y, fmaf(y4.w, w3.y, acc.y))));
        acc.z = fmaf(y4.x, w0.z, fmaf(y4.y, w1.z, fmaf(y4.z, w2.z, fmaf(y4.w, w3.z, acc.z))));
        acc.w = fmaf(y4.x, w0.w, fmaf(y4.y, w1.w, fmaf(y4.z, w2.w, fmaf(y4.w, w3.w, acc.w))));
    }
    if (oq < 32) {
        ((float4*)(poseP + pos * 128))[oq] = acc;
    } else {
        int oo = (oq - 32) * 4;
        float* ad = aP + pos * 8 + oo;
        ad[0] = 1.f / (1.f + expf(-acc.x));
        ad[1] = 1.f / (1.f + expf(-acc.y));
        ad[2] = 1.f / (1.f + expf(-acc.z));
        ad[3] = 1.f / (1.f + expf(-acc.w));
    }
}

// ---------------- capsule layer with fuzzy routing (2-pass fused) ----------------
template<int N, int C, int K, int S, int H, int W, int Bi, int OH, int OW, bool COORDS, int BLK>
__global__ __launch_bounds__(BLK) void k_caps(
    const float* __restrict__ pose_in,  // (b,H,W,Bi,16)
    const float* __restrict__ a_in,     // (b,H,W,Bi)
    const float* __restrict__ Wt,       // transposed weights (r-major)
    const float* __restrict__ bu, const float* __restrict__ ba,
    float* __restrict__ pose_out,       // (b,OH,OW,C,16)
    float* __restrict__ a_out)          // (b,OH,OW,C)
{
    constexpr int NW  = BLK / 64;                 // waves per block
    constexpr int NIG = BLK / 16;                 // # i-groups
    constexpr int NIT = (N + NIG - 1) / NIG;      // i iterations per thread

    __shared__ __align__(16) float pp[N * 16];
    __shared__ float ap[N];
    __shared__ float coeff0[N];
    __shared__ float mu0[16 * 17];
    __shared__ float red1[NW * C * 17];
    __shared__ float red2[NW * C * 17];
    __shared__ float redr[NW * C];

    const int t = threadIdx.x;
    const int lane = t & 63;
    const int w = t >> 6;
    const int n_ = blockIdx.x;
    const int b = n_ / (OH * OW);
    const int rem = n_ % (OH * OW);
    const int oh = rem / OW, ow = rem % OW;

    // ---- gather patch pose (float4) and activation into LDS ----
    for (int idx = t; idx < N * 4; idx += BLK) {
        int i = idx >> 2, f = idx & 3;
        int bi = i % Bi;
        int sh, sw;
        if constexpr (COORDS) { int hw = i / Bi; sw = hw % W; sh = hw / W; }
        else { int k2 = i / Bi; sw = ow * S + (k2 % K); sh = oh * S + (k2 / K); }
        const float4* src = (const float4*)(pose_in + (((b * H + sh) * W + sw) * Bi + bi) * 16);
        ((float4*)(pp + i * 16))[f] = src[f];
    }
    for (int i = t; i < N; i += BLK) {
        int bi = i % Bi;
        int sh, sw;
        if constexpr (COORDS) { int hw = i / Bi; sw = hw % W; sh = hw / W; }
        else { int k2 = i / Bi; sw = ow * S + (k2 % K); sh = oh * S + (k2 / K); }
        ap[i] = a_in[((b * H + sh) * W + sw) * Bi + bi];
    }
    __syncthreads();

    // ---- coeff0[i] = a[i] / (sum a + C^2*EPS) ----
    {
        float part = 0.f;
        for (int i = t; i < N; i += BLK) part += ap[i];
        #pragma unroll
        for (int m = 1; m < 64; m <<= 1) part += __shfl_xor(part, m, 64);
        if (lane == 0) red1[w] = part;
        __syncthreads();
        float s = 0.f;
        #pragma unroll
        for (int ww = 0; ww < NW; ++ww) s += red1[ww];
        float inv0 = 1.f / (s + (float)(C * C) * EPS_);
        for (int i = t; i < N; i += BLK) coeff0[i] = ap[i] * inv0;
        __syncthreads();
    }

    const int ig = t >> 4, cc = t & 15;

    // ================= pass A: mu0 =================
    {
        float muU[16];
        #pragma unroll
        for (int e2 = 0; e2 < 16; ++e2) muU[e2] = 0.f;
        if (cc < C) {
            for (int ii = 0; ii < NIT; ++ii) {
                int i = ig + ii * NIG;
                if (i < N) {
                    const float4* pi4 = (const float4*)(pp + i * 16);
                    int widx = COORDS ? (i % Bi) : i;
                    const float4* wt4 = (const float4*)(Wt + (widx * C + cc) * 16);
                    float4 pv[4] = { pi4[0], pi4[1], pi4[2], pi4[3] };
                    float4 wv[4] = { wt4[0], wt4[1], wt4[2], wt4[3] };
                    float co = coeff0[i];
                    float chv = 0.f, cwv = 0.f;
                    if constexpr (COORDS) {
                        chv = (float)(i / (W * Bi)) * (1.f / H);
                        cwv = (float)((i / Bi) % W) * (1.f / W);
                    }
                    #pragma unroll
                    for (int e2 = 0; e2 < 16; ++e2) {
                        float4 p4 = pv[e2 >> 2], w4 = wv[e2 & 3];
                        float v = p4.x * w4.x + p4.y * w4.y + p4.z * w4.z + p4.w * w4.w;
                        if constexpr (COORDS) { if (e2 == 0) v += chv; if (e2 == 1) v += cwv; }
                        muU[e2] = fmaf(co, v, muU[e2]);
                    }
                }
            }
        }
        #pragma unroll
        for (int e2 = 0; e2 < 16; ++e2) {
            float xv = muU[e2];
            xv += __shfl_xor(xv, 16, 64);
            xv += __shfl_xor(xv, 32, 64);
            if (lane < 16 && lane < C) red1[(w * C + lane) * 17 + e2] = xv;
        }
        __syncthreads();
        if (t < 256) {
            int c = t >> 4, e = t & 15;
            if (c < C) {
                float m = 0.f;
                #pragma unroll
                for (int ww = 0; ww < NW; ++ww) m += red1[(ww * C + c) * 17 + e];
                mu0[c * 17 + e] = m;
            }
        }
        __syncthreads();
    }

    // ================= pass B: dist -> rm fused with Sv/Sv2/rsum =================
    {
        float m0[16];
        if (cc < C) {
            #pragma unroll
            for (int e2 = 0; e2 < 16; ++e2) m0[e2] = mu0[cc * 17 + e2];
        }
        float SvU[16], Sv2U[16];
        #pragma unroll
        for (int e2 = 0; e2 < 16; ++e2) { SvU[e2] = 0.f; Sv2U[e2] = 0.f; }
        float rsumP = 0.f;

        for (int ii = 0; ii < NIT; ++ii) {
            int i = ig + ii * NIG;
            bool act = (i < N);
            float inv = 0.f;
            float vv[16];
            if (act && cc < C) {
                const float4* pi4 = (const float4*)(pp + i * 16);
                int widx = COORDS ? (i % Bi) : i;
                const float4* wt4 = (const float4*)(Wt + (widx * C + cc) * 16);
                float4 pv[4] = { pi4[0], pi4[1], pi4[2], pi4[3] };
                float4 wv[4] = { wt4[0], wt4[1], wt4[2], wt4[3] };
                float chv = 0.f, cwv = 0.f;
                if constexpr (COORDS) {
                    chv = (float)(i / (W * Bi)) * (1.f / H);
                    cwv = (float)((i / Bi) % W) * (1.f / W);
                }
                float dist = EPS_;
                #pragma unroll
                for (int e2 = 0; e2 < 16; ++e2) {
                    float4 p4 = pv[e2 >> 2], w4 = wv[e2 & 3];
                    float v = p4.x * w4.x + p4.y * w4.y + p4.z * w4.z + p4.w * w4.w;
                    if constexpr (COORDS) { if (e2 == 0) v += chv; if (e2 == 1) v += cwv; }
                    vv[e2] = v;
                    float d = v - m0[e2];
                    dist = fmaf(d, d, dist);
                }
                inv = 1.f / dist;
            }
            float s = inv;
            #pragma unroll
            for (int m = 1; m < 16; m <<= 1) s += __shfl_xor(s, m, 64);
            if (act && cc < C) {
                float r1 = inv / (s + EPS_);
                float rm = r1 * r1 * ap[i];
                rsumP += rm;
                #pragma unroll
                for (int e2 = 0; e2 < 16; ++e2) {
                    SvU[e2] = fmaf(rm, vv[e2], SvU[e2]);
                    Sv2U[e2] = fmaf(rm * vv[e2], vv[e2], Sv2U[e2]);
                }
            }
        }
        #pragma unroll
        for (int e2 = 0; e2 < 16; ++e2) {
            float xv = SvU[e2];
            xv += __shfl_xor(xv, 16, 64);
            xv += __shfl_xor(xv, 32, 64);
            float yv = Sv2U[e2];
            yv += __shfl_xor(yv, 16, 64);
            yv += __shfl_xor(yv, 32, 64);
            if (lane < 16 && lane < C) {
                red1[(w * C + lane) * 17 + e2] = xv;
                red2[(w * C + lane) * 17 + e2] = yv;
            }
        }
        {
            float rv = rsumP;
            rv += __shfl_xor(rv, 16, 64);
            rv += __shfl_xor(rv, 32, 64);
            if (lane < 16 && lane < C) redr[w * C + lane] = rv;
        }
        __syncthreads();
    }

    // ================= epilogue =================
    if (t < 256) {
        int c = t >> 4, e = t & 15;
        if (c < C) {
            float SvT = 0.f, Sv2T = 0.f, R = 0.f;
            #pragma unroll
            for (int ww = 0; ww < NW; ++ww) {
                SvT  += red1[(ww * C + c) * 17 + e];
                Sv2T += red2[(ww * C + c) * 17 + e];
                R    += redr[ww * C + c];
            }
            float id = 1.f / (R + EPS_);
            float S0 = R * id;
            float Sv = SvT * id;           // mu1
            float Sv2 = Sv2T * id;
            float sigma = fmaxf(Sv2 + Sv * Sv * (S0 - 2.f), 0.f) + EPS_;
            float cost = (bu[c] + 0.5f * logf(sigma)) * R;
            float cs = cost;
            #pragma unroll
            for (int m = 1; m < 16; m <<= 1) cs += __shfl_xor(cs, m, 64);  // sum over e
            if constexpr (!COORDS) {
                pose_out[(n_ * C + c) * 16 + e] = Sv;
                if (e == 0) a_out[n_ * C + c] = 1.f / (1.f + expf(-(LAM_ * (ba[c] - cs))));
            } else {
                if (e == 0) a_out[b * C + c] = 1.f / (1.f + expf(-(LAM_ * (ba[c] - cs))));
            }
        }
    }
}

extern "C" void kernel_launch(void* const* d_in, const int* in_sizes, int n_in,
                              void* d_out, int out_size, void* d_ws, size_t ws_size,
                              hipStream_t stream)
{
    const float* x   = (const float*)d_in[0];
    const float* c1w = (const float*)d_in[1];
    const float* c1b = (const float*)d_in[2];
    const float* bng = (const float*)d_in[3];
    const float* bnb = (const float*)d_in[4];
    const float* bnm = (const float*)d_in[5];
    const float* bnv = (const float*)d_in[6];
    const float* ppw = (const float*)d_in[7];
    const float* ppb = (const float*)d_in[8];
    const float* paw = (const float*)d_in[9];
    const float* pab = (const float*)d_in[10];
    const float* w1  = (const float*)d_in[11];
    const float* bu1 = (const float*)d_in[12];
    const float* ba1 = (const float*)d_in[13];
    const float* w2  = (const float*)d_in[14];
    const float* bu2 = (const float*)d_in[15];
    const float* ba2 = (const float*)d_in[16];
    const float* wcp = (const float*)d_in[17];
    const float* buc = (const float*)d_in[18];
    const float* bac = (const float*)d_in[19];
    float* out = (float*)d_out;

    float* ws    = (float*)d_ws;
    float* y     = ws;               // 64*16*16*64      = 1048576
    float* poseP = y + 1048576;      // 64*16*16*128     = 2097152
    float* aP    = poseP + 2097152;  // 64*16*16*8       = 131072
    float* pose1 = aP + 131072;      // 64*7*7*16*16     = 802816
    float* a1    = pose1 + 802816;   // 64*7*7*16        = 50176
    float* pose2 = a1 + 50176;       // 64*5*5*16*16     = 409600
    float* a2    = pose2 + 409600;   // 64*5*5*16        = 25600
    float* w1t   = a2 + 25600;       // 18432
    float* w2t   = w1t + 18432;      // 36864
    float* wct   = w2t + 36864;      // 2560
    float* wpt   = wct + 2560;       // 65*136 = 8840

    hipLaunchKernelGGL(k_transw, dim3((3616 * 16 + 65 * 136 + 255) / 256), dim3(256), 0, stream,
                       w1, w2, wcp, ppw, ppb, paw, pab, w1t, w2t, wct, wpt);
    hipLaunchKernelGGL(k_conv_bn, dim3(4096), dim3(256), 0, stream,
                       x, c1w, c1b, bng, bnb, bnm, bnv, y);
    hipLaunchKernelGGL(k_prim, dim3((16384 * 34 + 255) / 256), dim3(256), 0, stream,
                       y, wpt, poseP, aP);
    // stage 1: N=72, C=16
    hipLaunchKernelGGL((k_caps<72, 16, 3, 2, 16, 16, 8, 7, 7, false, 256>), dim3(64 * 7 * 7), dim3(256), 0, stream,
                       poseP, aP, w1t, bu1, ba1, pose1, a1);
    // stage 2: N=144, C=16
    hipLaunchKernelGGL((k_caps<144, 16, 3, 1, 7, 7, 16, 5, 5, false, 256>), dim3(64 * 5 * 5), dim3(256), 0, stream,
                       pose1, a1, w2t, bu2, ba2, pose2, a2);
    // class: N=400, C=10, coords, BLK=1024
    hipLaunchKernelGGL((k_caps<400, 10, 1, 1, 5, 5, 16, 1, 1, true, 1024>), dim3(64), dim3(1024), 0, stream,
                       pose2, a2, wct, buc, bac, nullptr, out);
}

// Round 5
// 253.790 us; speedup vs baseline: 1.9621x; 1.1069x over previous
//
#include <hip/hip_runtime.h>
#include <math.h>

#define EPS_ 1e-8f
#define LAM_ 1e-3f

// ---------------- K1: 5x5 conv s2 p2 + BN + ReLU ----------------
__global__ __launch_bounds__(256) void k_conv_bn(
    const float* __restrict__ x, const float* __restrict__ cw, const float* __restrict__ cb,
    const float* __restrict__ g, const float* __restrict__ bb,
    const float* __restrict__ mean, const float* __restrict__ var,
    float* __restrict__ y)
{
    int t = blockIdx.x * 256 + threadIdx.x;          // < 64*16*16*64
    int ch = t & 63, w = (t >> 6) & 15, h = (t >> 10) & 15, b = t >> 14;
    const float* xb = x + b * 1024;
    const float* wc = cw + ch * 25;
    float acc = cb[ch];
    #pragma unroll
    for (int kh = 0; kh < 5; ++kh) {
        int ih = h * 2 - 2 + kh;
        if (ih < 0 || ih > 31) continue;
        #pragma unroll
        for (int kw = 0; kw < 5; ++kw) {
            int iw = w * 2 - 2 + kw;
            if (iw < 0 || iw > 31) continue;
            acc = fmaf(xb[ih * 32 + iw], wc[kh * 5 + kw], acc);
        }
    }
    float v = (acc - mean[ch]) * (g[ch] * rsqrtf(var[ch] + 1e-3f)) + bb[ch];
    y[t] = fmaxf(v, 0.f);
}

// ---------------- K-prep: all weight transposes ----------------
__global__ __launch_bounds__(256) void k_transw(
    const float* __restrict__ w1, const float* __restrict__ w2, const float* __restrict__ wc,
    const float* __restrict__ pw, const float* __restrict__ pb,
    const float* __restrict__ aw, const float* __restrict__ ab,
    float* __restrict__ w1t, float* __restrict__ w2t, float* __restrict__ wct,
    float* __restrict__ wpt)
{
    int t = blockIdx.x * 256 + threadIdx.x;
    if (t < 3616 * 16) {
        int m = t >> 4, e = t & 15, r = e >> 2, q = e & 3;
        const float* src; float* dst;
        if (m < 1152)      { src = w1 + m * 16;          dst = w1t + m * 16; }
        else if (m < 3456) { src = w2 + (m - 1152) * 16; dst = w2t + (m - 1152) * 16; }
        else               { src = wc + (m - 3456) * 16; dst = wct + (m - 3456) * 16; }
        dst[e] = src[q * 4 + r];
    } else if (t < 3616 * 16 + 65 * 136) {
        int idx = t - 3616 * 16;
        int o = idx % 136, j = idx / 136;
        float v;
        if (j == 64)       v = (o < 128) ? pb[o] : ab[o - 128];
        else if (o < 128)  v = pw[o * 64 + j];
        else               v = aw[(o - 128) * 64 + j];
        wpt[j * 136 + o] = v;
    }
}

// ---------------- K2: primary caps (coalesced GEMM) ----------------
__global__ __launch_bounds__(256) void k_prim(
    const float* __restrict__ y, const float* __restrict__ wpt,
    float* __restrict__ poseP, float* __restrict__ aP)
{
    int t = blockIdx.x * 256 + threadIdx.x;
    if (t >= 16384 * 34) return;
    int oq = t % 34;
    int pos = t / 34;
    const float* yp = y + pos * 64;
    float4 acc = *(const float4*)(wpt + 64 * 136 + oq * 4);   // bias row
    #pragma unroll
    for (int j0 = 0; j0 < 64; j0 += 4) {
        float4 y4 = *(const float4*)(yp + j0);
        float4 w0 = *(const float4*)(wpt + (j0 + 0) * 136 + oq * 4);
        float4 w1 = *(const float4*)(wpt + (j0 + 1) * 136 + oq * 4);
        float4 w2 = *(const float4*)(wpt + (j0 + 2) * 136 + oq * 4);
        float4 w3 = *(const float4*)(wpt + (j0 + 3) * 136 + oq * 4);
        acc.x = fmaf(y4.x, w0.x, fmaf(y4.y, w1.x, fmaf(y4.z, w2.x, fmaf(y4.w, w3.x, acc.x))));
        acc.y = fmaf(y4.x, w0.y, fmaf(y4.y, w1.y, fmaf(y4.z, w2.y, fmaf(y4.w, w3.y, acc.y))));
        acc.z = fmaf(y4.x, w0.z, fmaf(y4.y, w1.z, fmaf(y4.z, w2.z, fmaf(y4.w, w3.z, acc.z))));
        acc.w = fmaf(y4.x, w0.w, fmaf(y4.y, w1.w, fmaf(y4.z, w2.w, fmaf(y4.w, w3.w, acc.w))));
    }
    if (oq < 32) {
        ((float4*)(poseP + pos * 128))[oq] = acc;
    } else {
        int oo = (oq - 32) * 4;
        float* ad = aP + pos * 8 + oo;
        ad[0] = 1.f / (1.f + __expf(-acc.x));
        ad[1] = 1.f / (1.f + __expf(-acc.y));
        ad[2] = 1.f / (1.f + __expf(-acc.z));
        ad[3] = 1.f / (1.f + __expf(-acc.w));
    }
}

// ---------------- wave-per-position capsule routing (stages 1 & 2) ----------------
// BLK=128: 2 waves, one position each, fully independent. Lane=(ig=lane>>4, cc=lane&15).
// All reductions in-wave via shfl; mu0/Sv/Sv2/rsum stay in registers.
template<int N, int C, int K, int S, int H, int W, int Bi, int OH, int OW>
__global__ __launch_bounds__(128) void k_caps_wave(
    const float* __restrict__ pose_in,  // (b,H,W,Bi,16)
    const float* __restrict__ a_in,     // (b,H,W,Bi)
    const float* __restrict__ Wt,       // (N,C,16) r-major transposed
    const float* __restrict__ bu, const float* __restrict__ ba,
    float* __restrict__ pose_out,       // (b,OH,OW,C,16)
    float* __restrict__ a_out)          // (b,OH,OW,C)
{
    static_assert(C == 16 && N % 4 == 0, "");
    constexpr int NIT = N / 4;

    __shared__ __align__(16) float pp[2 * N * 16];
    __shared__ float ap[2 * N];

    const int t = threadIdx.x;
    const int w = t >> 6, lane = t & 63;
    float* ppw = pp + w * N * 16;
    float* apw = ap + w * N;

    const int n_ = blockIdx.x * 2 + w;
    const int b = n_ / (OH * OW);
    const int rem = n_ % (OH * OW);
    const int oh = rem / OW, ow = rem % OW;

    // ---- gather patch pose (float4) and activation into this wave's LDS slice ----
    for (int idx = lane; idx < N * 4; idx += 64) {
        int i = idx >> 2, f = idx & 3;
        int bi = i % Bi;
        int k2 = i / Bi;
        int sw = ow * S + (k2 % K), sh = oh * S + (k2 / K);
        const float4* src = (const float4*)(pose_in + (((b * H + sh) * W + sw) * Bi + bi) * 16);
        ((float4*)(ppw + i * 16))[f] = src[f];
    }
    for (int i = lane; i < N; i += 64) {
        int bi = i % Bi;
        int k2 = i / Bi;
        int sw = ow * S + (k2 % K), sh = oh * S + (k2 / K);
        apw[i] = a_in[((b * H + sh) * W + sw) * Bi + bi];
    }
    __syncthreads();

    // ---- inv0 = 1 / (sum a + C^2*EPS) ----
    float suma = 0.f;
    for (int i = lane; i < N; i += 64) suma += apw[i];
    #pragma unroll
    for (int m = 1; m < 64; m <<= 1) suma += __shfl_xor(suma, m, 64);
    const float inv0 = __builtin_amdgcn_rcpf(suma + (float)(C * C) * EPS_);

    const int ig = t >> 4 & 3, cc = t & 15;

    // ================= pass A: mu0 (ends fully in registers) =================
    float muU[16];
    #pragma unroll
    for (int e2 = 0; e2 < 16; ++e2) muU[e2] = 0.f;
    #pragma unroll 2
    for (int ii = 0; ii < NIT; ++ii) {
        int i = ig + ii * 4;
        const float4* pi4 = (const float4*)(ppw + i * 16);
        const float4* wt4 = (const float4*)(Wt + (i * C + cc) * 16);
        float4 pv[4] = { pi4[0], pi4[1], pi4[2], pi4[3] };
        float4 wv[4] = { wt4[0], wt4[1], wt4[2], wt4[3] };
        float co = apw[i] * inv0;
        #pragma unroll
        for (int e2 = 0; e2 < 16; ++e2) {
            float4 p4 = pv[e2 >> 2], w4 = wv[e2 & 3];
            float v = p4.x * w4.x + p4.y * w4.y + p4.z * w4.z + p4.w * w4.w;
            muU[e2] = fmaf(co, v, muU[e2]);
        }
    }
    #pragma unroll
    for (int e2 = 0; e2 < 16; ++e2) {
        muU[e2] += __shfl_xor(muU[e2], 16, 64);
        muU[e2] += __shfl_xor(muU[e2], 32, 64);   // every lane: mu0[cc][e2]
    }

    // ================= pass B: dist -> rm fused with Sv/Sv2/rsum =================
    float SvU[16], Sv2U[16];
    #pragma unroll
    for (int e2 = 0; e2 < 16; ++e2) { SvU[e2] = 0.f; Sv2U[e2] = 0.f; }
    float rsum = 0.f;
    #pragma unroll 2
    for (int ii = 0; ii < NIT; ++ii) {
        int i = ig + ii * 4;
        const float4* pi4 = (const float4*)(ppw + i * 16);
        const float4* wt4 = (const float4*)(Wt + (i * C + cc) * 16);
        float4 pv[4] = { pi4[0], pi4[1], pi4[2], pi4[3] };
        float4 wv[4] = { wt4[0], wt4[1], wt4[2], wt4[3] };
        float vv[16];
        float dist = EPS_;
        #pragma unroll
        for (int e2 = 0; e2 < 16; ++e2) {
            float4 p4 = pv[e2 >> 2], w4 = wv[e2 & 3];
            float v = p4.x * w4.x + p4.y * w4.y + p4.z * w4.z + p4.w * w4.w;
            vv[e2] = v;
            float d = v - muU[e2];
            dist = fmaf(d, d, dist);
        }
        float inv = __builtin_amdgcn_rcpf(dist);
        float s = inv;
        #pragma unroll
        for (int m = 1; m < 16; m <<= 1) s += __shfl_xor(s, m, 64);   // sum over cc
        float r1 = inv * __builtin_amdgcn_rcpf(s + EPS_);
        float rm = r1 * r1 * apw[i];
        rsum += rm;
        #pragma unroll
        for (int e2 = 0; e2 < 16; ++e2) {
            float rv = rm * vv[e2];
            SvU[e2] += rv;
            Sv2U[e2] = fmaf(rv, vv[e2], Sv2U[e2]);
        }
    }
    #pragma unroll
    for (int e2 = 0; e2 < 16; ++e2) {
        SvU[e2] += __shfl_xor(SvU[e2], 16, 64);
        SvU[e2] += __shfl_xor(SvU[e2], 32, 64);
        Sv2U[e2] += __shfl_xor(Sv2U[e2], 16, 64);
        Sv2U[e2] += __shfl_xor(Sv2U[e2], 32, 64);
    }
    rsum += __shfl_xor(rsum, 16, 64);
    rsum += __shfl_xor(rsum, 32, 64);

    // ================= epilogue (all in registers; lanes 0-15 store) =================
    const float id = 1.f / (rsum + EPS_);
    const float S0 = rsum * id;
    const float buc_ = bu[cc];
    float cs = 0.f;
    float4 outv[4];
    #pragma unroll
    for (int e2 = 0; e2 < 16; ++e2) {
        float Sv = SvU[e2] * id;
        float Sv2 = Sv2U[e2] * id;
        float sigma = fmaxf(Sv2 + Sv * Sv * (S0 - 2.f), 0.f) + EPS_;
        cs += (buc_ + 0.5f * __logf(sigma)) * rsum;
        ((float*)outv)[e2] = Sv;
    }
    if (lane < 16) {
        float4* pd = (float4*)(pose_out + (n_ * C + cc) * 16);
        pd[0] = outv[0]; pd[1] = outv[1]; pd[2] = outv[2]; pd[3] = outv[3];
        a_out[n_ * C + cc] = 1.f / (1.f + __expf(-(LAM_ * (ba[cc] - cs))));
    }
}

// ---------------- block-wide caps (class layer, COORDS) ----------------
template<int N, int C, int H, int W, int Bi, int BLK>
__global__ __launch_bounds__(BLK) void k_caps_class(
    const float* __restrict__ pose_in, const float* __restrict__ a_in,
    const float* __restrict__ Wt,
    const float* __restrict__ bu, const float* __restrict__ ba,
    float* __restrict__ a_out)
{
    constexpr int NW  = BLK / 64;
    constexpr int NIG = BLK / 16;
    constexpr int NIT = (N + NIG - 1) / NIG;

    __shared__ __align__(16) float pp[N * 16];
    __shared__ float ap[N];
    __shared__ float coeff0[N];
    __shared__ float mu0[16 * 17];
    __shared__ float red1[NW * C * 17];
    __shared__ float red2[NW * C * 17];
    __shared__ float redr[NW * C];

    const int t = threadIdx.x;
    const int lane = t & 63;
    const int w = t >> 6;
    const int b = blockIdx.x;

    for (int idx = t; idx < N * 4; idx += BLK) {
        int i = idx >> 2, f = idx & 3;
        int bi = i % Bi;
        int hw = i / Bi;
        int sw = hw % W, sh = hw / W;
        const float4* src = (const float4*)(pose_in + (((b * H + sh) * W + sw) * Bi + bi) * 16);
        ((float4*)(pp + i * 16))[f] = src[f];
    }
    for (int i = t; i < N; i += BLK) {
        int bi = i % Bi;
        int hw = i / Bi;
        int sw = hw % W, sh = hw / W;
        ap[i] = a_in[((b * H + sh) * W + sw) * Bi + bi];
    }
    __syncthreads();

    {
        float part = 0.f;
        for (int i = t; i < N; i += BLK) part += ap[i];
        #pragma unroll
        for (int m = 1; m < 64; m <<= 1) part += __shfl_xor(part, m, 64);
        if (lane == 0) red1[w] = part;
        __syncthreads();
        float s = 0.f;
        #pragma unroll
        for (int ww = 0; ww < NW; ++ww) s += red1[ww];
        float inv0 = 1.f / (s + (float)(C * C) * EPS_);
        for (int i = t; i < N; i += BLK) coeff0[i] = ap[i] * inv0;
        __syncthreads();
    }

    const int ig = t >> 4, cc = t & 15;

    // pass A
    {
        float muU[16];
        #pragma unroll
        for (int e2 = 0; e2 < 16; ++e2) muU[e2] = 0.f;
        if (cc < C) {
            for (int ii = 0; ii < NIT; ++ii) {
                int i = ig + ii * NIG;
                if (i < N) {
                    const float4* pi4 = (const float4*)(pp + i * 16);
                    const float4* wt4 = (const float4*)(Wt + ((i % Bi) * C + cc) * 16);
                    float4 pv[4] = { pi4[0], pi4[1], pi4[2], pi4[3] };
                    float4 wv[4] = { wt4[0], wt4[1], wt4[2], wt4[3] };
                    float co = coeff0[i];
                    float chv = (float)(i / (W * Bi)) * (1.f / H);
                    float cwv = (float)((i / Bi) % W) * (1.f / W);
                    #pragma unroll
                    for (int e2 = 0; e2 < 16; ++e2) {
                        float4 p4 = pv[e2 >> 2], w4 = wv[e2 & 3];
                        float v = p4.x * w4.x + p4.y * w4.y + p4.z * w4.z + p4.w * w4.w;
                        if (e2 == 0) v += chv;
                        if (e2 == 1) v += cwv;
                        muU[e2] = fmaf(co, v, muU[e2]);
                    }
                }
            }
        }
        #pragma unroll
        for (int e2 = 0; e2 < 16; ++e2) {
            float xv = muU[e2];
            xv += __shfl_xor(xv, 16, 64);
            xv += __shfl_xor(xv, 32, 64);
            if (lane < 16 && lane < C) red1[(w * C + lane) * 17 + e2] = xv;
        }
        __syncthreads();
        if (t < 256) {
            int c = t >> 4, e = t & 15;
            if (c < C) {
                float m = 0.f;
                #pragma unroll
                for (int ww = 0; ww < NW; ++ww) m += red1[(ww * C + c) * 17 + e];
                mu0[c * 17 + e] = m;
            }
        }
        __syncthreads();
    }

    // pass B
    {
        float m0[16];
        if (cc < C) {
            #pragma unroll
            for (int e2 = 0; e2 < 16; ++e2) m0[e2] = mu0[cc * 17 + e2];
        }
        float SvU[16], Sv2U[16];
        #pragma unroll
        for (int e2 = 0; e2 < 16; ++e2) { SvU[e2] = 0.f; Sv2U[e2] = 0.f; }
        float rsumP = 0.f;

        for (int ii = 0; ii < NIT; ++ii) {
            int i = ig + ii * NIG;
            bool act = (i < N);
            float inv = 0.f;
            float vv[16];
            if (act && cc < C) {
                const float4* pi4 = (const float4*)(pp + i * 16);
                const float4* wt4 = (const float4*)(Wt + ((i % Bi) * C + cc) * 16);
                float4 pv[4] = { pi4[0], pi4[1], pi4[2], pi4[3] };
                float4 wv[4] = { wt4[0], wt4[1], wt4[2], wt4[3] };
                float chv = (float)(i / (W * Bi)) * (1.f / H);
                float cwv = (float)((i / Bi) % W) * (1.f / W);
                float dist = EPS_;
                #pragma unroll
                for (int e2 = 0; e2 < 16; ++e2) {
                    float4 p4 = pv[e2 >> 2], w4 = wv[e2 & 3];
                    float v = p4.x * w4.x + p4.y * w4.y + p4.z * w4.z + p4.w * w4.w;
                    if (e2 == 0) v += chv;
                    if (e2 == 1) v += cwv;
                    vv[e2] = v;
                    float d = v - m0[e2];
                    dist = fmaf(d, d, dist);
                }
                inv = 1.f / dist;
            }
            float s = inv;
            #pragma unroll
            for (int m = 1; m < 16; m <<= 1) s += __shfl_xor(s, m, 64);
            if (act && cc < C) {
                float r1 = inv / (s + EPS_);
                float rm = r1 * r1 * ap[i];
                rsumP += rm;
                #pragma unroll
                for (int e2 = 0; e2 < 16; ++e2) {
                    SvU[e2] = fmaf(rm, vv[e2], SvU[e2]);
                    Sv2U[e2] = fmaf(rm * vv[e2], vv[e2], Sv2U[e2]);
                }
            }
        }
        #pragma unroll
        for (int e2 = 0; e2 < 16; ++e2) {
            float xv = SvU[e2];
            xv += __shfl_xor(xv, 16, 64);
            xv += __shfl_xor(xv, 32, 64);
            float yv = Sv2U[e2];
            yv += __shfl_xor(yv, 16, 64);
            yv += __shfl_xor(yv, 32, 64);
            if (lane < 16 && lane < C) {
                red1[(w * C + lane) * 17 + e2] = xv;
                red2[(w * C + lane) * 17 + e2] = yv;
            }
        }
        {
            float rv = rsumP;
            rv += __shfl_xor(rv, 16, 64);
            rv += __shfl_xor(rv, 32, 64);
            if (lane < 16 && lane < C) redr[w * C + lane] = rv;
        }
        __syncthreads();
    }

    if (t < 256) {
        int c = t >> 4, e = t & 15;
        if (c < C) {
            float SvT = 0.f, Sv2T = 0.f, R = 0.f;
            #pragma unroll
            for (int ww = 0; ww < NW; ++ww) {
                SvT  += red1[(ww * C + c) * 17 + e];
                Sv2T += red2[(ww * C + c) * 17 + e];
                R    += redr[ww * C + c];
            }
            float id = 1.f / (R + EPS_);
            float S0 = R * id;
            float Sv = SvT * id;
            float Sv2 = Sv2T * id;
            float sigma = fmaxf(Sv2 + Sv * Sv * (S0 - 2.f), 0.f) + EPS_;
            float cost = (bu[c] + 0.5f * logf(sigma)) * R;
            float cs = cost;
            #pragma unroll
            for (int m = 1; m < 16; m <<= 1) cs += __shfl_xor(cs, m, 64);
            if (e == 0) a_out[b * C + c] = 1.f / (1.f + expf(-(LAM_ * (ba[c] - cs))));
        }
    }
}

extern "C" void kernel_launch(void* const* d_in, const int* in_sizes, int n_in,
                              void* d_out, int out_size, void* d_ws, size_t ws_size,
                              hipStream_t stream)
{
    const float* x   = (const float*)d_in[0];
    const float* c1w = (const float*)d_in[1];
    const float* c1b = (const float*)d_in[2];
    const float* bng = (const float*)d_in[3];
    const float* bnb = (const float*)d_in[4];
    const float* bnm = (const float*)d_in[5];
    const float* bnv = (const float*)d_in[6];
    const float* ppw = (const float*)d_in[7];
    const float* ppb = (const float*)d_in[8];
    const float* paw = (const float*)d_in[9];
    const float* pab = (const float*)d_in[10];
    const float* w1  = (const float*)d_in[11];
    const float* bu1 = (const float*)d_in[12];
    const float* ba1 = (const float*)d_in[13];
    const float* w2  = (const float*)d_in[14];
    const float* bu2 = (const float*)d_in[15];
    const float* ba2 = (const float*)d_in[16];
    const float* wcp = (const float*)d_in[17];
    const float* buc = (const float*)d_in[18];
    const float* bac = (const float*)d_in[19];
    float* out = (float*)d_out;

    float* ws    = (float*)d_ws;
    float* y     = ws;               // 64*16*16*64      = 1048576
    float* poseP = y + 1048576;      // 64*16*16*128     = 2097152
    float* aP    = poseP + 2097152;  // 64*16*16*8       = 131072
    float* pose1 = aP + 131072;      // 64*7*7*16*16     = 802816
    float* a1    = pose1 + 802816;   // 64*7*7*16        = 50176
    float* pose2 = a1 + 50176;       // 64*5*5*16*16     = 409600
    float* a2    = pose2 + 409600;   // 64*5*5*16        = 25600
    float* w1t   = a2 + 25600;       // 18432
    float* w2t   = w1t + 18432;      // 36864
    float* wct   = w2t + 36864;      // 2560
    float* wpt   = wct + 2560;       // 65*136 = 8840

    hipLaunchKernelGGL(k_transw, dim3((3616 * 16 + 65 * 136 + 255) / 256), dim3(256), 0, stream,
                       w1, w2, wcp, ppw, ppb, paw, pab, w1t, w2t, wct, wpt);
    hipLaunchKernelGGL(k_conv_bn, dim3(4096), dim3(256), 0, stream,
                       x, c1w, c1b, bng, bnb, bnm, bnv, y);
    hipLaunchKernelGGL(k_prim, dim3((16384 * 34 + 255) / 256), dim3(256), 0, stream,
                       y, wpt, poseP, aP);
    // stage 1: N=72, C=16, 3136 positions -> 1568 blocks x 128
    hipLaunchKernelGGL((k_caps_wave<72, 16, 3, 2, 16, 16, 8, 7, 7>), dim3(1568), dim3(128), 0, stream,
                       poseP, aP, w1t, bu1, ba1, pose1, a1);
    // stage 2: N=144, C=16, 1600 positions -> 800 blocks x 128
    hipLaunchKernelGGL((k_caps_wave<144, 16, 3, 1, 7, 7, 16, 5, 5>), dim3(800), dim3(128), 0, stream,
                       pose1, a1, w2t, bu2, ba2, pose2, a2);
    // class: N=400, C=10, coords, BLK=1024
    hipLaunchKernelGGL((k_caps_class<400, 10, 5, 5, 16, 1024>), dim3(64), dim3(1024), 0, stream,
                       pose2, a2, wct, buc, bac, out);
}